// Round 20
// baseline (32.992 us; speedup 1.0000x reference)
//
#include <hip/hip_runtime.h>

constexpr int B = 64, N = 8732, C = 21, M = 16;
constexpr int TROW = 1 + 6 * M;       // 97
constexpr int NBIN = 2048;            // windowed bins (2 float16-key steps wide)
constexpr unsigned BASE16 = 15103u;   // key16 window start
constexpr int NSLAB = 8;
constexpr int TILE = 256;             // rows per tile
constexpr int NTILES = (N + TILE - 1) / TILE;  // 35 (last tile = 28 rows)
constexpr int BPB = 16;               // blocks per batch -> 1024 blocks = 4/CU
constexpr float FSCALE = 262144.0f;   // 2^18 fixed-point for CE sums
constexpr unsigned long long CNT1 = 1ull << 44;
constexpr unsigned long long FIXMASK = (1ull << 44) - 1;

typedef __attribute__((address_space(1))) const unsigned int g_as_t;
typedef __attribute__((address_space(3))) unsigned int l_as_t;

__device__ __forceinline__ unsigned f2key(float f) {
  unsigned u = __float_as_uint(f);
  return (u & 0x80000000u) ? ~u : (u | 0x80000000u);
}
__device__ __forceinline__ float key2f(unsigned k) {
  unsigned u = (k & 0x80000000u) ? (k ^ 0x80000000u) : ~k;
  return __uint_as_float(u);
}

// ---- zero the slabs (8 * 2048 u64 = 128 KB) ----
__global__ __launch_bounds__(256) void k_zero(unsigned long long* __restrict__ z) {
  int idx = blockIdx.x * 256 + threadIdx.x;   // 64 blocks * 256
  z[idx] = 0ull;
}

// ---- logp: SINGLE-buffer async staging + row-to-registers.
// ---- LDS 37.9KB -> 4 blocks/CU (2x R15's in-flight capacity); per tile:
// ---- regs <- own row; barrier; async-stage next tile into same buffer;
// ---- compute from regs under the stage; barrier (drains stage). ----
__global__ __launch_bounds__(256) void k_logp(
    const float* __restrict__ conf, const float* __restrict__ bbox,
    const float* __restrict__ target, const float* __restrict__ pred,
    unsigned long long* __restrict__ slab1, float4* __restrict__ batchCtl) {
  __shared__ __align__(16) float sbuf[TILE * C];       // 21504 B
  __shared__ unsigned long long shist[NBIN];           // 16384 B
  __shared__ int sk[M];
  int b = blockIdx.y, bx = blockIdx.x, tid = threadIdx.x;
  int wave = tid >> 6, lane = tid & 63;

  for (int i = tid; i < NBIN; i += 256) shist[i] = 0ull;
  const float* tr = target + (size_t)b * TROW;
  if (tid < M) {
    int num = (int)tr[0];
    sk[tid] = (tid < num) ? (int)tr[1 + 6 * tid + 5] : -1;
  }

  const size_t cbase = (size_t)b * N;
  int nt = (NTILES - 1 - bx) / BPB + 1;   // 3 for bx<3, else 2

  // async stage of tile kt into sbuf: 1KB chunks; chunk c by wave c%4;
  // LDS dest = uniform chunk base + lane*16 (HW rule, m104).
#define STAGE(kt)                                                           \
  {                                                                         \
    int tt_ = bx + (kt) * BPB;                                              \
    int n0_ = tt_ * TILE;                                                   \
    int rows_ = min(TILE, N - n0_);                                         \
    int bytes_ = rows_ * C * 4;  /* 16B-divisible (rows%4==0) */            \
    const char* gb_ = (const char*)(conf + (cbase + n0_) * C);              \
    char* lb_ = (char*)sbuf;                                                \
    for (int c_ = wave; c_ * 1024 < bytes_; c_ += 4) {                      \
      int off_ = c_ * 1024 + lane * 16;                                     \
      if (off_ + 16 <= bytes_) {                                            \
        __builtin_amdgcn_global_load_lds((g_as_t*)(gb_ + off_),             \
                                         (l_as_t*)(lb_ + c_ * 1024),        \
                                         16, 0, 0);                         \
      }                                                                     \
    }                                                                       \
  }

  STAGE(0);
  __syncthreads();   // tile0 resident

  for (int t = 0; t < nt; ++t) {
    int tt_ = bx + t * BPB;
    int n0_ = tt_ * TILE;
    int rows_ = min(TILE, N - n0_);
    // 1) own row -> registers (private; survives buffer reuse)
    float r[C];
    if (tid < rows_) {
      const float* x = sbuf + tid * C;
      #pragma unroll
      for (int c = 0; c < C; c++) r[c] = x[c];
    }
    __syncthreads();                    // all reads of sbuf complete
    // 2) fire next tile into the SAME buffer; streams under the compute
    if (t + 1 < nt) STAGE(t + 1);
    // 3) compute from registers
    if (tid < rows_) {
      int n = n0_ + tid;
      float s0 = __expf(r[0]) + __expf(r[4]) + __expf(r[8]) + __expf(r[12]) + __expf(r[16]);
      float s1 = __expf(r[1]) + __expf(r[5]) + __expf(r[9]) + __expf(r[13]) + __expf(r[17]);
      float s2 = __expf(r[2]) + __expf(r[6]) + __expf(r[10]) + __expf(r[14]) + __expf(r[18]);
      float s3 = __expf(r[3]) + __expf(r[7]) + __expf(r[11]) + __expf(r[15]) + __expf(r[19]);
      float s = (s0 + s1) + (s2 + s3) + __expf(r[20]);
      float lp = r[0] - __logf(s);
      bool asg = false;
      for (int j = 0; j < M; j++) asg |= (sk[j] == n);
      if (!asg) {
        int idx = ((int)(f2key(lp) >> 16) - (int)BASE16) >> 1;
        idx = min(max(idx, 0), NBIN - 1);
        atomicAdd(&shist[idx],
                  CNT1 | (unsigned long long)((-lp) * FSCALE + 0.5f));
      }
    }
    __syncthreads();   // drains the stage (vmcnt0) -> next tile resident
  }
#undef STAGE

  unsigned long long* sg = slab1 + (size_t)(bx & (NSLAB - 1)) * NBIN;
  for (int i = tid; i < NBIN; i += 256) {
    unsigned long long v = shist[i];
    if (v) atomicAdd(&sg[i], v);
  }

  if (bx == 0) {
    float myValid = 0.f, myPos = 0.f, myCE = 0.f, mySL = 0.f;
    if (tid < M && sk[tid] >= 0) {
      const float* e = tr + 1 + 6 * tid;
      int cls = (int)e[0];
      float tx1 = e[1], ty1 = e[2], tx2 = e[3], ty2 = e[4];
      int k = sk[tid];
      float p0 = pred[k * 4 + 0], p1 = pred[k * 4 + 1];
      float p2 = pred[k * 4 + 2], p3 = pred[k * 4 + 3];
      float pw = p2 - p0, ph = p3 - p1;
      float pcx = (p0 + p2) * 0.5f, pcy = (p1 + p3) * 0.5f;
      float tw = tx2 - tx1, th = ty2 - ty1;
      float tcx = (tx1 + tx2) * 0.5f, tcy = (ty1 + ty2) * 0.5f;
      float ebv[4];
      ebv[0] = (tcx - pcx) / pw;
      ebv[1] = (tcy - pcy) / ph;
      ebv[2] = __logf(tw / pw);
      ebv[3] = __logf(th / ph);
      const float* bo = bbox + ((size_t)b * N + k) * 4;
      float sl = 0.f;
      for (int j = 0; j < 4; j++) {
        float d = bo[j] - ebv[j];
        float ad = fabsf(d);
        sl += (ad < 1.f) ? 0.5f * d * d : ad - 0.5f;
      }
      myValid = 1.f; mySL = sl;
      if (cls > 0) {
        const float* x = conf + ((size_t)b * N + k) * C;
        float s = 0.f;
        for (int c = 0; c < C; c++) s += __expf(x[c]);
        float lp = x[cls] - __logf(s);
        myPos = 1.f; myCE = -lp;
      }
    }
    if (tid < 64) {
      for (int off = 32; off; off >>= 1) {
        myValid += __shfl_down(myValid, off, 64);
        myPos   += __shfl_down(myPos, off, 64);
        myCE    += __shfl_down(myCE, off, 64);
        mySL    += __shfl_down(mySL, off, 64);
      }
      if (tid == 0) batchCtl[b] = make_float4(myPos, myValid, myCE, mySL);
    }
  }
}

// ---- fin: reduce slabs + scan + interpolate + outputs (1 block, 1024 thr) ----
__global__ __launch_bounds__(1024) void k_fin(
    const unsigned long long* __restrict__ slab1,
    const float4* __restrict__ batchCtl, float* __restrict__ out) {
  __shared__ unsigned long long sm[NBIN];      // 16 KB
  __shared__ unsigned long long sscan[1024];   // 8 KB
  __shared__ unsigned srank;
  __shared__ float sp, sva, sce, ssl;
  __shared__ double sNeg;
  int tid = threadIdx.x;

  if (tid < 64) {
    float4 v = batchCtl[tid];
    float p = v.x, va = v.y, ce = v.z, sl = v.w;
    for (int off = 32; off; off >>= 1) {
      p  += __shfl_down(p, off, 64);
      va += __shfl_down(va, off, 64);
      ce += __shfl_down(ce, off, 64);
      sl += __shfl_down(sl, off, 64);
    }
    if (tid == 0) {
      sp = p; sva = va; sce = ce; ssl = sl;
      srank = 3u * (unsigned)(p + 0.5f);
      sNeg = 0.0;
    }
  }

  for (int k = 0; k < NBIN / 1024; k++) {
    int bin = tid + k * 1024;
    unsigned long long v = 0ull;
    for (int s = 0; s < NSLAB; s++) v += slab1[(size_t)s * NBIN + bin];
    sm[bin] = v;
  }
  __syncthreads();

  unsigned long long h2[2];
  unsigned long long part = 0ull;
  for (int j = 0; j < 2; j++) { h2[j] = sm[tid * 2 + j]; part += h2[j]; }
  sscan[tid] = part;
  __syncthreads();
  for (int off = 1; off < 1024; off <<= 1) {
    unsigned long long add = (tid >= off) ? sscan[tid - off] : 0ull;
    __syncthreads();
    sscan[tid] += add;
    __syncthreads();
  }

  unsigned rank = srank;
  if (rank) {
    unsigned long long cum = sscan[tid] - part;
    for (int j = 0; j < 2; j++) {
      unsigned long long h = h2[j];
      unsigned c0 = (unsigned)(cum >> 44);
      unsigned c1 = (unsigned)((cum + h) >> 44);
      if (c0 < rank && c1 >= rank) {
        unsigned t = (unsigned)(tid * 2 + j);
        unsigned r = rank - c0;
        unsigned long long fixBelow = cum & FIXMASK;
        float ceEdge = -key2f((BASE16 + 2u * t) << 16);
        sNeg = (double)fixBelow / 262144.0 + (double)r * (double)ceEdge;
      }
      cum += h;
    }
  }
  __syncthreads();
  if (tid == 0) {
    out[0] = (sce + (float)sNeg) / fmaxf(4.0f * sp, 1.0f);
    out[1] = ssl / fmaxf(4.0f * sva, 1.0f);
  }
}

extern "C" void kernel_launch(void* const* d_in, const int* in_sizes, int n_in,
                              void* d_out, int out_size, void* d_ws, size_t ws_size,
                              hipStream_t stream) {
  const float* conf = (const float*)d_in[0];
  const float* bbox = (const float*)d_in[1];
  const float* target = (const float*)d_in[2];
  const float* pred = (const float*)d_in[3];
  float* out = (float*)d_out;

  char* ws = (char*)d_ws;
  unsigned long long* slab1 = (unsigned long long*)ws;
  size_t off = (size_t)NSLAB * NBIN * 8;                // 128 KB
  float4* batchCtl = (float4*)(ws + off); off += 64 * 16;

  k_zero<<<64, 256, 0, stream>>>(slab1);
  k_logp<<<dim3(BPB, B), 256, 0, stream>>>(conf, bbox, target, pred,
                                           slab1, batchCtl);
  k_fin<<<1, 1024, 0, stream>>>(slab1, batchCtl, out);
}

// Round 21
// 26.664 us; speedup vs baseline: 1.2373x; 1.2373x over previous
//
#include <hip/hip_runtime.h>

constexpr int B = 64, N = 8732, C = 21, M = 16;
constexpr int TROW = 1 + 6 * M;       // 97
constexpr int NBIN = 1024;            // windowed bins (4 float16-key steps wide)
constexpr unsigned BASE16 = 15103u;   // key16 window start (4096 key16 values)
constexpr int NSLAB = 8;
constexpr int TILE = 256;             // rows per tile
constexpr int NTILES = (N + TILE - 1) / TILE;  // 35 (last tile = 28 rows)
constexpr int BPB = 8;                // blocks per batch -> 512 blocks = 2/CU
constexpr float FSCALE = 262144.0f;   // 2^18 fixed-point for CE sums
constexpr unsigned long long CNT1 = 1ull << 44;
constexpr unsigned long long FIXMASK = (1ull << 44) - 1;

typedef __attribute__((address_space(1))) const unsigned int g_as_t;
typedef __attribute__((address_space(3))) unsigned int l_as_t;

__device__ __forceinline__ unsigned f2key(float f) {
  unsigned u = __float_as_uint(f);
  return (u & 0x80000000u) ? ~u : (u | 0x80000000u);
}
__device__ __forceinline__ float key2f(unsigned k) {
  unsigned u = (k & 0x80000000u) ? (k ^ 0x80000000u) : ~k;
  return __uint_as_float(u);
}

// counted-vmcnt barrier: tile t+1 (oldest outstanding) completes, tile t+2's
// 5-6 loads stay in flight. Rule #18: sched_barrier fences around raw asm.
__device__ __forceinline__ void pipe_barrier_vm5() {
  asm volatile("s_waitcnt vmcnt(5) lgkmcnt(0)" ::: "memory");
  __builtin_amdgcn_sched_barrier(0);
  __builtin_amdgcn_s_barrier();
  __builtin_amdgcn_sched_barrier(0);
}
__device__ __forceinline__ void pipe_barrier_vm0() {
  asm volatile("s_waitcnt vmcnt(0) lgkmcnt(0)" ::: "memory");
  __builtin_amdgcn_sched_barrier(0);
  __builtin_amdgcn_s_barrier();
  __builtin_amdgcn_sched_barrier(0);
}

// ---- zero the slabs (8 * 1024 u64 = 64 KB) ----
__global__ __launch_bounds__(256) void k_zero(unsigned long long* __restrict__ z) {
  int idx = blockIdx.x * 256 + threadIdx.x;   // 32 blocks * 256
  z[idx] = 0ull;
}

// ---- logp: TRIPLE-buffer async global_load_lds pipeline, counted vmcnt.
// ---- Two tiles stream concurrently; barrier never drains the newest stage. ----
__global__ __launch_bounds__(256) void k_logp(
    const float* __restrict__ conf, const float* __restrict__ bbox,
    const float* __restrict__ target, const float* __restrict__ pred,
    unsigned long long* __restrict__ slab1, float4* __restrict__ batchCtl) {
  __shared__ __align__(16) float sbuf[3][TILE * C];    // 64512 B
  __shared__ unsigned long long shist[NBIN];           // 8192 B
  __shared__ int sk[M];
  int b = blockIdx.y, bx = blockIdx.x, tid = threadIdx.x;
  int wave = tid >> 6, lane = tid & 63;

  for (int i = tid; i < NBIN; i += 256) shist[i] = 0ull;
  const float* tr = target + (size_t)b * TROW;
  if (tid < M) {
    int num = (int)tr[0];
    sk[tid] = (tid < num) ? (int)tr[1 + 6 * tid + 5] : -1;
  }

  const size_t cbase = (size_t)b * N;
  int nt = (NTILES - 1 - bx) / BPB + 1;   // 5 for bx<3, else 4 (always >=4)

  // async stage of tile kt into sbuf[bi]: 1KB chunks; chunk c by wave c%4;
  // per-wave 5-6 issues; LDS dest = uniform chunk base + lane*16 (m104 rule).
#define STAGE(kt, bi)                                                       \
  {                                                                         \
    int tt_ = bx + (kt) * BPB;                                              \
    int n0_ = tt_ * TILE;                                                   \
    int rows_ = min(TILE, N - n0_);                                         \
    int bytes_ = rows_ * C * 4;  /* 16B-divisible (rows%4==0) */            \
    const char* gb_ = (const char*)(conf + (cbase + n0_) * C);              \
    char* lb_ = (char*)sbuf[bi];                                            \
    for (int c_ = wave; c_ * 1024 < bytes_; c_ += 4) {                      \
      int off_ = c_ * 1024 + lane * 16;                                     \
      if (off_ + 16 <= bytes_) {                                            \
        __builtin_amdgcn_global_load_lds((g_as_t*)(gb_ + off_),             \
                                         (l_as_t*)(lb_ + c_ * 1024),        \
                                         16, 0, 0);                         \
      }                                                                     \
    }                                                                       \
  }

  // prologue: tiles 0 and 1 both in flight; vm5 completes tile0 only
  STAGE(0, 0);
  STAGE(1, 1);
  pipe_barrier_vm5();

  for (int t = 0; t < nt; ++t) {
    if (t + 2 < nt) STAGE(t + 2, (t + 2) % 3);   // 2 tiles now in flight
    {
      int tt_ = bx + t * BPB;
      int n0_ = tt_ * TILE;
      int rows_ = min(TILE, N - n0_);
      if (tid < rows_) {
        int n = n0_ + tid;
        const float* x = sbuf[t % 3] + tid * C;
        float s0 = __expf(x[0]) + __expf(x[4]) + __expf(x[8]) + __expf(x[12]) + __expf(x[16]);
        float s1 = __expf(x[1]) + __expf(x[5]) + __expf(x[9]) + __expf(x[13]) + __expf(x[17]);
        float s2 = __expf(x[2]) + __expf(x[6]) + __expf(x[10]) + __expf(x[14]) + __expf(x[18]);
        float s3 = __expf(x[3]) + __expf(x[7]) + __expf(x[11]) + __expf(x[15]) + __expf(x[19]);
        float s = (s0 + s1) + (s2 + s3) + __expf(x[20]);
        float lp = x[0] - __logf(s);
        bool asg = false;
        for (int j = 0; j < M; j++) asg |= (sk[j] == n);
        if (!asg) {
          int idx = ((int)(f2key(lp) >> 16) - (int)BASE16) >> 2;
          idx = min(max(idx, 0), NBIN - 1);
          atomicAdd(&shist[idx],
                    CNT1 | (unsigned long long)((-lp) * FSCALE + 0.5f));
        }
      }
    }
    if (t + 1 < nt) {
      if (t + 2 < nt) pipe_barrier_vm5();   // t+1 complete; t+2 stays in flight
      else            pipe_barrier_vm0();   // epilogue: drain all
    }
  }
#undef STAGE

  __syncthreads();   // full drain + hist visibility before merge

  unsigned long long* sg = slab1 + (size_t)(bx & (NSLAB - 1)) * NBIN;
  for (int i = tid; i < NBIN; i += 256) {
    unsigned long long v = shist[i];
    if (v) atomicAdd(&sg[i], v);
  }

  if (bx == 0) {
    float myValid = 0.f, myPos = 0.f, myCE = 0.f, mySL = 0.f;
    if (tid < M && sk[tid] >= 0) {
      const float* e = tr + 1 + 6 * tid;
      int cls = (int)e[0];
      float tx1 = e[1], ty1 = e[2], tx2 = e[3], ty2 = e[4];
      int k = sk[tid];
      float p0 = pred[k * 4 + 0], p1 = pred[k * 4 + 1];
      float p2 = pred[k * 4 + 2], p3 = pred[k * 4 + 3];
      float pw = p2 - p0, ph = p3 - p1;
      float pcx = (p0 + p2) * 0.5f, pcy = (p1 + p3) * 0.5f;
      float tw = tx2 - tx1, th = ty2 - ty1;
      float tcx = (tx1 + tx2) * 0.5f, tcy = (ty1 + ty2) * 0.5f;
      float ebv[4];
      ebv[0] = (tcx - pcx) / pw;
      ebv[1] = (tcy - pcy) / ph;
      ebv[2] = __logf(tw / pw);
      ebv[3] = __logf(th / ph);
      const float* bo = bbox + ((size_t)b * N + k) * 4;
      float sl = 0.f;
      for (int j = 0; j < 4; j++) {
        float d = bo[j] - ebv[j];
        float ad = fabsf(d);
        sl += (ad < 1.f) ? 0.5f * d * d : ad - 0.5f;
      }
      myValid = 1.f; mySL = sl;
      if (cls > 0) {
        const float* x = conf + ((size_t)b * N + k) * C;
        float s = 0.f;
        for (int c = 0; c < C; c++) s += __expf(x[c]);
        float lp = x[cls] - __logf(s);
        myPos = 1.f; myCE = -lp;
      }
    }
    if (tid < 64) {
      for (int off = 32; off; off >>= 1) {
        myValid += __shfl_down(myValid, off, 64);
        myPos   += __shfl_down(myPos, off, 64);
        myCE    += __shfl_down(myCE, off, 64);
        mySL    += __shfl_down(mySL, off, 64);
      }
      if (tid == 0) batchCtl[b] = make_float4(myPos, myValid, myCE, mySL);
    }
  }
}

// ---- fin: reduce slabs + scan + interpolate + outputs (1 block, 1024 thr) ----
__global__ __launch_bounds__(1024) void k_fin(
    const unsigned long long* __restrict__ slab1,
    const float4* __restrict__ batchCtl, float* __restrict__ out) {
  __shared__ unsigned long long sscan[1024];   // 8 KB
  __shared__ unsigned srank;
  __shared__ float sp, sva, sce, ssl;
  __shared__ double sNeg;
  int tid = threadIdx.x;

  if (tid < 64) {
    float4 v = batchCtl[tid];
    float p = v.x, va = v.y, ce = v.z, sl = v.w;
    for (int off = 32; off; off >>= 1) {
      p  += __shfl_down(p, off, 64);
      va += __shfl_down(va, off, 64);
      ce += __shfl_down(ce, off, 64);
      sl += __shfl_down(sl, off, 64);
    }
    if (tid == 0) {
      sp = p; sva = va; sce = ce; ssl = sl;
      srank = 3u * (unsigned)(p + 0.5f);
      sNeg = 0.0;
    }
  }

  // one bin per thread
  unsigned long long hv = 0ull;
  for (int s = 0; s < NSLAB; s++) hv += slab1[(size_t)s * NBIN + tid];
  sscan[tid] = hv;
  __syncthreads();
  for (int off = 1; off < 1024; off <<= 1) {
    unsigned long long add = (tid >= off) ? sscan[tid - off] : 0ull;
    __syncthreads();
    sscan[tid] += add;
    __syncthreads();
  }

  unsigned rank = srank;
  if (rank) {
    unsigned long long cum = sscan[tid] - hv;
    unsigned c0 = (unsigned)(cum >> 44);
    unsigned c1 = (unsigned)((cum + hv) >> 44);
    if (c0 < rank && c1 >= rank) {
      unsigned r = rank - c0;
      unsigned long long fixBelow = cum & FIXMASK;
      float ceEdge = -key2f((BASE16 + 4u * (unsigned)tid) << 16);
      sNeg = (double)fixBelow / 262144.0 + (double)r * (double)ceEdge;
    }
  }
  __syncthreads();
  if (tid == 0) {
    out[0] = (sce + (float)sNeg) / fmaxf(4.0f * sp, 1.0f);
    out[1] = ssl / fmaxf(4.0f * sva, 1.0f);
  }
}

extern "C" void kernel_launch(void* const* d_in, const int* in_sizes, int n_in,
                              void* d_out, int out_size, void* d_ws, size_t ws_size,
                              hipStream_t stream) {
  const float* conf = (const float*)d_in[0];
  const float* bbox = (const float*)d_in[1];
  const float* target = (const float*)d_in[2];
  const float* pred = (const float*)d_in[3];
  float* out = (float*)d_out;

  char* ws = (char*)d_ws;
  unsigned long long* slab1 = (unsigned long long*)ws;
  size_t off = (size_t)NSLAB * NBIN * 8;                // 64 KB
  float4* batchCtl = (float4*)(ws + off); off += 64 * 16;

  k_zero<<<32, 256, 0, stream>>>(slab1);
  k_logp<<<dim3(BPB, B), 256, 0, stream>>>(conf, bbox, target, pred,
                                           slab1, batchCtl);
  k_fin<<<1, 1024, 0, stream>>>(slab1, batchCtl, out);
}